// Round 1
// baseline (15410.728 us; speedup 1.0000x reference)
//
#include <hip/hip_runtime.h>
#include <hip/hip_bf16.h>
#include <math.h>

// ---------------------------------------------------------------------------
// BayerKP: demosaic kernel-prediction network.
//   mosaic (2,3,768,768) f32 -> out (2,3,748,748) f32
// Pipeline:
//   split      : gray = sum_c mosaic; x0 = [g0,b,r,g1] (2,4,384,384)
//   conv0..3   : 3x3 VALID + ReLU, 64 ch       (384->382->380->378->376)
//   conv4      : 3x3 VALID, 490 ch (strips)    (376->374)
//   epilogue   : per-pixel softmax(49/98) weighted 7x7 gathers + pixel shuffle
// ---------------------------------------------------------------------------

__global__ __launch_bounds__(256) void split_k(const float* __restrict__ mosaic,
                                               float* __restrict__ x0) {
    // mosaic [2][3][768][768] -> x0 [2][4][384][384]
    int idx = blockIdx.x * 256 + threadIdx.x;
    const int total = 2 * 4 * 384 * 384;
    if (idx >= total) return;
    int x = idx % 384;
    int t = idx / 384;
    int y = t % 384;  t /= 384;
    int c = t % 4;
    int b = t / 4;
    // c=0: g0(2y,2x)  c=1: b(2y+1,2x)  c=2: r(2y,2x+1)  c=3: g1(2y+1,2x+1)
    int Y = 2 * y + ((c == 1 || c == 3) ? 1 : 0);
    int X = 2 * x + ((c == 2 || c == 3) ? 1 : 0);
    const float* mb = mosaic + (size_t)b * 3 * 768 * 768;
    float g = mb[Y * 768 + X] + mb[768 * 768 + Y * 768 + X] + mb[2 * 768 * 768 + Y * 768 + X];
    x0[idx] = g;
}

// Direct 3x3 VALID conv. Tile: 64 x-pixels, 16 output channels per block.
// Block 256 = 64 px * 4 ocq; each thread accumulates 4 output channels.
// Writes rows [y_start, y_start+y_count) of the output into a buffer whose
// leading spatial dim is y_count (strip support for conv4).
template <int CIN, bool RELU>
__global__ __launch_bounds__(256) void conv3x3_k(
    const float* __restrict__ in,   // [B][CIN][Hin][Win]
    int Hin, int Win,
    const float* __restrict__ W,    // [Cout][CIN][3][3]
    const float* __restrict__ bias, // [Cout]
    float* __restrict__ out,        // [B][Cout][y_count][Wout]
    int Cout, int y_start, int y_count) {
    const int Wout = Win - 2;
    const int nOcg = (Cout + 15) / 16;
    const int tx = blockIdx.x;
    const int yo = blockIdx.y;
    const int zb = blockIdx.z;
    const int b   = zb / nOcg;
    const int ocg = zb % nOcg;
    const int y  = y_start + yo;
    const int x0 = tx * 64;
    const int tid = threadIdx.x;
    const int px  = tid & 63;
    const int ocq = tid >> 6;  // wave-uniform

    __shared__ float smem[CIN * 3 * 66];

    // stage input window rows y..y+2, cols x0..x0+65
    for (int e = tid; e < CIN * 3 * 66; e += 256) {
        int ic  = e / 198;
        int rem = e % 198;
        int r   = rem / 66;
        int c   = rem % 66;
        int gx  = x0 + c;
        float v = 0.f;
        if (gx < Win) v = in[(((size_t)b * CIN + ic) * Hin + (y + r)) * Win + gx];
        smem[(ic * 3 + r) * 66 + c] = v;
    }
    __syncthreads();

    const int ocb = ocg * 16 + ocq * 4;
    const float* wp[4];
#pragma unroll
    for (int o = 0; o < 4; ++o) {
        int ocr = ocb + o; if (ocr >= Cout) ocr = Cout - 1;  // clamp (store guarded)
        wp[o] = W + (size_t)ocr * CIN * 9;
    }

    float acc0 = 0.f, acc1 = 0.f, acc2 = 0.f, acc3 = 0.f;
    for (int ic = 0; ic < CIN; ++ic) {
        const float* srow = smem + ic * 198;
        const int wic = ic * 9;
#pragma unroll
        for (int ky = 0; ky < 3; ++ky) {
            float i0 = srow[ky * 66 + px];
            float i1 = srow[ky * 66 + px + 1];
            float i2 = srow[ky * 66 + px + 2];
            const float* w0 = wp[0] + wic + ky * 3;
            const float* w1 = wp[1] + wic + ky * 3;
            const float* w2 = wp[2] + wic + ky * 3;
            const float* w3 = wp[3] + wic + ky * 3;
            acc0 = fmaf(i0, w0[0], acc0); acc0 = fmaf(i1, w0[1], acc0); acc0 = fmaf(i2, w0[2], acc0);
            acc1 = fmaf(i0, w1[0], acc1); acc1 = fmaf(i1, w1[1], acc1); acc1 = fmaf(i2, w1[2], acc1);
            acc2 = fmaf(i0, w2[0], acc2); acc2 = fmaf(i1, w2[1], acc2); acc2 = fmaf(i2, w2[2], acc2);
            acc3 = fmaf(i0, w3[0], acc3); acc3 = fmaf(i1, w3[1], acc3); acc3 = fmaf(i2, w3[2], acc3);
        }
    }

    const int x = x0 + px;
    if (x < Wout) {
        float accs[4] = {acc0, acc1, acc2, acc3};
#pragma unroll
        for (int o = 0; o < 4; ++o) {
            int oc = ocb + o;
            if (oc < Cout) {
                float v = accs[o] + bias[oc];
                if (RELU) v = fmaxf(v, 0.f);
                out[(((size_t)b * Cout + oc) * y_count + yo) * Wout + x] = v;
            }
        }
    }
}

// Epilogue: per half-res pixel, 8 tasks = {red0,red1,red2, blue0,blue1,blue2,
// green0, green1}. Each task: softmax over its 49 (98 for green) conv4
// channels, then softmax-weighted 7x7 gather from the half-res plane(s),
// written into the pixel-shuffled full-res output. Raw passthrough channels
// ride along on tasks 0/3/6/7.
__global__ __launch_bounds__(256) void epilogue_k(
    const float* __restrict__ kst,  // [B][490][y_count][374]
    const float* __restrict__ x0,   // [B][4][384][384]
    float* __restrict__ out,        // [B][3][748][748]
    int y_start, int y_count) {
    const int tid  = threadIdx.x;
    const int px   = tid & 31;
    const int task = tid >> 5;  // 0..7
    const int x  = blockIdx.x * 32 + px;
    const int yo = blockIdx.y;
    const int b  = blockIdx.z;
    const int y  = y_start + yo;
    if (x >= 374) return;

    const float* g0 = x0 + ((size_t)b * 4 + 0) * 384 * 384;
    const float* bl = x0 + ((size_t)b * 4 + 1) * 384 * 384;
    const float* rr = x0 + ((size_t)b * 4 + 2) * 384 * 384;
    const float* g1 = x0 + ((size_t)b * 4 + 3) * 384 * 384;

    int ch0, cnt, color, oy, ox;
    const float* p0;
    const float* p1 = nullptr;
    switch (task) {
        // red buf order: [f0, raw_r, f1, f2] -> pos (0,0)=f0 (1,0)=f1 (1,1)=f2
        case 0: ch0 = 0;   cnt = 49; p0 = rr; color = 0; oy = 0; ox = 0; break;
        case 1: ch0 = 49;  cnt = 49; p0 = rr; color = 0; oy = 1; ox = 0; break;
        case 2: ch0 = 98;  cnt = 49; p0 = rr; color = 0; oy = 1; ox = 1; break;
        // blue buf order: [f0, f1, raw_b, f2] -> (0,0)=f0 (0,1)=f1 (1,1)=f2
        case 3: ch0 = 147; cnt = 49; p0 = bl; color = 2; oy = 0; ox = 0; break;
        case 4: ch0 = 196; cnt = 49; p0 = bl; color = 2; oy = 0; ox = 1; break;
        case 5: ch0 = 245; cnt = 49; p0 = bl; color = 2; oy = 1; ox = 1; break;
        // green buf order: [raw_g0, f0, f1, raw_g1] -> (0,1)=f0 (1,0)=f1
        case 6: ch0 = 294; cnt = 98; p0 = g0; p1 = g1; color = 1; oy = 0; ox = 1; break;
        default: ch0 = 392; cnt = 98; p0 = g0; p1 = g1; color = 1; oy = 1; ox = 0; break;
    }

    const size_t kstride = (size_t)y_count * 374;
    const float* kb = kst + (((size_t)b * 490 + ch0) * y_count + yo) * 374 + x;

    float m = -1e30f;
    for (int q = 0; q < cnt; ++q) m = fmaxf(m, kb[q * kstride]);

    float den = 0.f, num = 0.f;
    for (int q = 0; q < cnt; ++q) {
        float e = __expf(kb[q * kstride] - m);
        den += e;
        int qq = (q < 49) ? q : q - 49;
        const float* pl = (q < 49) ? p0 : p1;
        num += e * pl[(y + 2 + qq / 7) * 384 + (x + 2 + qq % 7)];
    }
    out[(((size_t)b * 3 + color) * 748 + (2 * y + oy)) * 748 + (2 * x + ox)] = num / den;

    // raw passthroughs (cropped half-res planes, offset +5)
    if (task == 0) out[(((size_t)b * 3 + 0) * 748 + 2 * y) * 748 + 2 * x + 1]       = rr[(y + 5) * 384 + x + 5];
    if (task == 3) out[(((size_t)b * 3 + 2) * 748 + 2 * y + 1) * 748 + 2 * x]       = bl[(y + 5) * 384 + x + 5];
    if (task == 6) out[(((size_t)b * 3 + 1) * 748 + 2 * y) * 748 + 2 * x]           = g0[(y + 5) * 384 + x + 5];
    if (task == 7) out[(((size_t)b * 3 + 1) * 748 + 2 * y + 1) * 748 + 2 * x + 1]   = g1[(y + 5) * 384 + x + 5];
}

extern "C" void kernel_launch(void* const* d_in, const int* in_sizes, int n_in,
                              void* d_out, int out_size, void* d_ws, size_t ws_size,
                              hipStream_t stream) {
    const float* mosaic = (const float*)d_in[0];
    const float* W0 = (const float*)d_in[1];  const float* b0 = (const float*)d_in[2];
    const float* W1 = (const float*)d_in[3];  const float* b1 = (const float*)d_in[4];
    const float* W2 = (const float*)d_in[5];  const float* b2 = (const float*)d_in[6];
    const float* W3 = (const float*)d_in[7];  const float* b3 = (const float*)d_in[8];
    const float* W4 = (const float*)d_in[9];  const float* b4 = (const float*)d_in[10];
    float* out = (float*)d_out;

    // workspace layout (floats):
    //   x0   : 2*4*384*384            = 1,179,648
    //   bufA : 2*64*382*382 (max a1/a3) = 18,678,272
    //   bufB : 2*64*380*380 (max a2/a4) = 18,483,200
    //   kst  : 2*490*34*374           = 12,461,680     total ~203 MB
    float* ws   = (float*)d_ws;
    float* x0   = ws;
    float* bufA = x0 + 1179648;
    float* bufB = bufA + 18678272;
    float* kst  = bufB + 18483200;

    split_k<<<(2 * 4 * 384 * 384 + 255) / 256, 256, 0, stream>>>(mosaic, x0);

    // conv0: 4->64, 384 -> 382, ReLU
    conv3x3_k<4, true><<<dim3(6, 382, 2 * 4), 256, 0, stream>>>(x0, 384, 384, W0, b0, bufA, 64, 0, 382);
    // conv1: 64->64, 382 -> 380
    conv3x3_k<64, true><<<dim3(6, 380, 2 * 4), 256, 0, stream>>>(bufA, 382, 382, W1, b1, bufB, 64, 0, 380);
    // conv2: 64->64, 380 -> 378
    conv3x3_k<64, true><<<dim3(6, 378, 2 * 4), 256, 0, stream>>>(bufB, 380, 380, W2, b2, bufA, 64, 0, 378);
    // conv3: 64->64, 378 -> 376
    conv3x3_k<64, true><<<dim3(6, 376, 2 * 4), 256, 0, stream>>>(bufA, 378, 378, W3, b3, bufB, 64, 0, 376);

    // conv4 (64->490, 376 -> 374, no ReLU) in 11 strips of 34 rows, each
    // immediately consumed by the fused softmax/gather/pixel-shuffle epilogue.
    const int nOcg4 = (490 + 15) / 16;  // 31
    for (int ys = 0; ys < 374; ys += 34) {
        const int yc = 34;
        conv3x3_k<64, false><<<dim3(6, yc, 2 * nOcg4), 256, 0, stream>>>(
            bufB, 376, 376, W4, b4, kst, 490, ys, yc);
        epilogue_k<<<dim3(12, yc, 2), 256, 0, stream>>>(kst, x0, out, ys, yc);
    }
}

// Round 2
// 1885.562 us; speedup vs baseline: 8.1730x; 8.1730x over previous
//
#include <hip/hip_runtime.h>
#include <hip/hip_bf16.h>
#include <math.h>

// ---------------------------------------------------------------------------
// BayerKP: demosaic kernel-prediction network (MFMA bf16 implicit-GEMM).
//   mosaic (2,3,768,768) f32 -> out (2,3,748,748) f32
//   split   : gray sum + 2x2 phase split -> x0f f32 (2,4,384,384) NCHW
//   conv0   : direct f32, 4->64, ReLU -> a1 NHWC bf16 (2,382,382,64)
//   conv1-3 : MFMA bf16 implicit GEMM (9-tap K loop), ReLU, NHWC bf16
//   conv4   : MFMA, 64->490(pad 512), f32 NHWC strips of 34 rows
//   epilogue: per-pixel softmax(49/98) weighted 7x7 gathers + pixel shuffle
// ---------------------------------------------------------------------------

typedef __attribute__((ext_vector_type(8))) short short8;
typedef __attribute__((ext_vector_type(4))) short short4v;
typedef __attribute__((ext_vector_type(4))) float f32x4;

static __device__ __forceinline__ short f2bf(float v) {
    __bf16 h = (__bf16)v;
    return __builtin_bit_cast(short, h);
}

__global__ __launch_bounds__(256) void split_k(const float* __restrict__ mosaic,
                                               float* __restrict__ x0) {
    int idx = blockIdx.x * 256 + threadIdx.x;
    const int total = 2 * 4 * 384 * 384;
    if (idx >= total) return;
    int x = idx % 384;
    int t = idx / 384;
    int y = t % 384;  t /= 384;
    int c = t % 4;
    int b = t / 4;
    int Y = 2 * y + ((c == 1 || c == 3) ? 1 : 0);
    int X = 2 * x + ((c == 2 || c == 3) ? 1 : 0);
    const float* mb = mosaic + (size_t)b * 3 * 768 * 768;
    float g = mb[Y * 768 + X] + mb[768 * 768 + Y * 768 + X] + mb[2 * 768 * 768 + Y * 768 + X];
    x0[idx] = g;
}

// repack W[Cout][64][3][3] f32 -> Wq[9][CoutP][64] bf16 (zero-pad oc >= Cout)
__global__ __launch_bounds__(256) void repack_k(const float* __restrict__ W,
                                                int Cout, int CoutP,
                                                short* __restrict__ dst) {
    int idx = blockIdx.x * 256 + threadIdx.x;
    int total = 9 * CoutP * 64;
    if (idx >= total) return;
    int ic = idx % 64;
    int t2 = idx / 64;
    int oc = t2 % CoutP;
    int t  = t2 / CoutP;
    float v = (oc < Cout) ? W[((size_t)oc * 64 + ic) * 9 + t] : 0.f;
    dst[idx] = f2bf(v);
}

// conv0: direct f32, Cin=4, 384->382, ReLU, output NHWC bf16 [b][y][x][64]
__global__ __launch_bounds__(256) void conv0_k(const float* __restrict__ x0f,
                                               const float* __restrict__ W0,
                                               const float* __restrict__ b0,
                                               short* __restrict__ out) {
    __shared__ float w[64 * 36];
    __shared__ float bb[64];
    for (int e = threadIdx.x; e < 64 * 36; e += 256) w[e] = W0[e];
    if (threadIdx.x < 64) bb[threadIdx.x] = b0[threadIdx.x];
    __syncthreads();
    int idx = blockIdx.x * 256 + threadIdx.x;
    if (idx >= 2 * 382 * 382) return;
    int x = idx % 382;
    int t = idx / 382;
    int y = t % 382;
    int b = t / 382;
    const float* base = x0f + (size_t)b * 4 * 384 * 384;
    float in[4][9];
#pragma unroll
    for (int ic = 0; ic < 4; ++ic)
#pragma unroll
        for (int ky = 0; ky < 3; ++ky)
#pragma unroll
            for (int kx = 0; kx < 3; ++kx)
                in[ic][ky * 3 + kx] = base[ic * 384 * 384 + (y + ky) * 384 + (x + kx)];
    short* op = out + (((size_t)b * 382 + y) * 382 + x) * 64;
    float accs[8];
    for (int og = 0; og < 8; ++og) {
#pragma unroll
        for (int oo = 0; oo < 8; ++oo) {
            int oc = og * 8 + oo;
            float acc = bb[oc];
            const float* wp = w + oc * 36;
#pragma unroll
            for (int ic = 0; ic < 4; ++ic)
#pragma unroll
                for (int e = 0; e < 9; ++e)
                    acc = fmaf(in[ic][e], wp[ic * 9 + e], acc);
            accs[oo] = fmaxf(acc, 0.f);
        }
        short8 pk;
#pragma unroll
        for (int oo = 0; oo < 8; ++oo) pk[oo] = f2bf(accs[oo]);
        *(short8*)(op + og * 8) = pk;
    }
}

// Implicit-GEMM 3x3 conv via mfma_f32_16x16x32_bf16.
// Block 256 = 4 waves (2x2). Tile: BM=64 oc x BN=64 px (one output row).
// K loop: 9 taps x Cin=64 (BK=64 per tap).
template <bool RELU, bool OUT_BF16>
__global__ __launch_bounds__(256) void convmfma_k(
    const short* __restrict__ act,   // NHWC bf16 [B][Hin][Win][64]
    int Hin, int Win,
    const short* __restrict__ Wq,    // [9][CoutP][64] bf16
    const float* __restrict__ bias,  // [Cout]
    void* __restrict__ outv,         // NHWC [B][y_count][Wout][ocStride]
    int Cout, int CoutP, int ocStride,
    int y_start, int y_count) {
    const int Wout = Win - 2;
    const int nOcg = CoutP >> 6;
    const int zb  = blockIdx.z;
    const int ocg = zb % nOcg;
    const int b   = zb / nOcg;
    const int yo  = blockIdx.y;
    const int y   = y_start + yo;
    const int x0  = blockIdx.x * 64;
    const int tid  = threadIdx.x;
    const int wave = tid >> 6;
    const int lane = tid & 63;
    const int wr = wave >> 1, wc = wave & 1;

    __shared__ __align__(16) short At[64][72];
    __shared__ __align__(16) short Bt[64][72];

    const int srow = tid >> 2;  // 0..63
    const int sq   = tid & 3;   // 16-ic chunk

    short8 ra0, ra1, rb0, rb1;
    auto loadA = [&](int tap) {
        const short* p = Wq + ((size_t)tap * CoutP + ocg * 64 + srow) * 64 + sq * 16;
        ra0 = *(const short8*)p;
        ra1 = *(const short8*)(p + 8);
    };
    auto loadB = [&](int tap) {
        int ky = tap / 3, kx = tap % 3;
        int xe = x0 + srow;
        if (xe > Wout - 1) xe = Wout - 1;
        xe += kx;
        const short* p = act + (((size_t)b * Hin + (y + ky)) * (size_t)Win + xe) * 64 + sq * 16;
        rb0 = *(const short8*)p;
        rb1 = *(const short8*)(p + 8);
    };

    f32x4 acc[2][2] = {};
    loadA(0);
    loadB(0);
#pragma unroll 1
    for (int tap = 0; tap < 9; ++tap) {
        if (tap) __syncthreads();
        *(short8*)&At[srow][sq * 16]     = ra0;
        *(short8*)&At[srow][sq * 16 + 8] = ra1;
        *(short8*)&Bt[srow][sq * 16]     = rb0;
        *(short8*)&Bt[srow][sq * 16 + 8] = rb1;
        __syncthreads();
        if (tap < 8) { loadA(tap + 1); loadB(tap + 1); }
        short8 af[2][2], bf[2][2];
#pragma unroll
        for (int kk = 0; kk < 2; ++kk) {
            int ic = kk * 32 + (lane >> 4) * 8;
#pragma unroll
            for (int m = 0; m < 2; ++m)
                af[kk][m] = *(const short8*)&At[wr * 32 + m * 16 + (lane & 15)][ic];
#pragma unroll
            for (int n = 0; n < 2; ++n)
                bf[kk][n] = *(const short8*)&Bt[wc * 32 + n * 16 + (lane & 15)][ic];
        }
#pragma unroll
        for (int kk = 0; kk < 2; ++kk)
#pragma unroll
            for (int m = 0; m < 2; ++m)
#pragma unroll
                for (int n = 0; n < 2; ++n)
                    acc[m][n] = __builtin_amdgcn_mfma_f32_16x16x32_bf16(
                        af[kk][m], bf[kk][n], acc[m][n], 0, 0, 0);
    }

#pragma unroll
    for (int m = 0; m < 2; ++m) {
        int ocb = ocg * 64 + wr * 32 + m * 16 + (lane >> 4) * 4;
#pragma unroll
        for (int n = 0; n < 2; ++n) {
            int x = x0 + wc * 32 + n * 16 + (lane & 15);
            if (x >= Wout) continue;
            size_t off = (((size_t)b * y_count + yo) * Wout + x) * ocStride + ocb;
            if (OUT_BF16) {
                // conv1-3: Cout==CoutP==64, no oc guard needed
                short4v pk;
#pragma unroll
                for (int r = 0; r < 4; ++r) {
                    float v = acc[m][n][r] + bias[ocb + r];
                    if (RELU) v = fmaxf(v, 0.f);
                    pk[r] = f2bf(v);
                }
                *(short4v*)((short*)outv + off) = pk;
            } else {
                float* op = (float*)outv + off;
#pragma unroll
                for (int r = 0; r < 4; ++r) {
                    int oc = ocb + r;
                    if (oc < Cout) {
                        float v = acc[m][n][r] + bias[oc];
                        if (RELU) v = fmaxf(v, 0.f);
                        op[r] = v;
                    }
                }
            }
        }
    }
}

// Epilogue: 8 tasks = {red0..2, blue0..2, green0, green1} per half-res pixel.
// kst is NHWC f32 [b][y_count][374][512].
__global__ __launch_bounds__(256) void epilogue_k(
    const float* __restrict__ kst,
    const float* __restrict__ x0,   // f32 NCHW [B][4][384][384]
    float* __restrict__ out,        // [B][3][748][748]
    int y_start, int y_count) {
    const int tid  = threadIdx.x;
    const int px   = tid & 31;
    const int task = tid >> 5;
    const int x  = blockIdx.x * 32 + px;
    const int yo = blockIdx.y;
    const int b  = blockIdx.z;
    const int y  = y_start + yo;
    if (x >= 374) return;

    const float* g0 = x0 + ((size_t)b * 4 + 0) * 384 * 384;
    const float* bl = x0 + ((size_t)b * 4 + 1) * 384 * 384;
    const float* rr = x0 + ((size_t)b * 4 + 2) * 384 * 384;
    const float* g1 = x0 + ((size_t)b * 4 + 3) * 384 * 384;

    int ch0, cnt, color, oy, ox;
    const float* p0;
    const float* p1 = nullptr;
    switch (task) {
        case 0: ch0 = 0;   cnt = 49; p0 = rr; color = 0; oy = 0; ox = 0; break;
        case 1: ch0 = 49;  cnt = 49; p0 = rr; color = 0; oy = 1; ox = 0; break;
        case 2: ch0 = 98;  cnt = 49; p0 = rr; color = 0; oy = 1; ox = 1; break;
        case 3: ch0 = 147; cnt = 49; p0 = bl; color = 2; oy = 0; ox = 0; break;
        case 4: ch0 = 196; cnt = 49; p0 = bl; color = 2; oy = 0; ox = 1; break;
        case 5: ch0 = 245; cnt = 49; p0 = bl; color = 2; oy = 1; ox = 1; break;
        case 6: ch0 = 294; cnt = 98; p0 = g0; p1 = g1; color = 1; oy = 0; ox = 1; break;
        default: ch0 = 392; cnt = 98; p0 = g0; p1 = g1; color = 1; oy = 1; ox = 0; break;
    }

    const float* kb = kst + (((size_t)b * y_count + yo) * 374 + x) * 512 + ch0;

    float m = -1e30f;
    for (int q = 0; q < cnt; ++q) m = fmaxf(m, kb[q]);

    float den = 0.f, num = 0.f;
    for (int q = 0; q < cnt; ++q) {
        float e = __expf(kb[q] - m);
        den += e;
        int qq = (q < 49) ? q : q - 49;
        const float* pl = (q < 49) ? p0 : p1;
        num += e * pl[(y + 2 + qq / 7) * 384 + (x + 2 + qq % 7)];
    }
    out[(((size_t)b * 3 + color) * 748 + (2 * y + oy)) * 748 + (2 * x + ox)] = num / den;

    if (task == 0) out[(((size_t)b * 3 + 0) * 748 + 2 * y) * 748 + 2 * x + 1]     = rr[(y + 5) * 384 + x + 5];
    if (task == 3) out[(((size_t)b * 3 + 2) * 748 + 2 * y + 1) * 748 + 2 * x]     = bl[(y + 5) * 384 + x + 5];
    if (task == 6) out[(((size_t)b * 3 + 1) * 748 + 2 * y) * 748 + 2 * x]         = g0[(y + 5) * 384 + x + 5];
    if (task == 7) out[(((size_t)b * 3 + 1) * 748 + 2 * y + 1) * 748 + 2 * x + 1] = g1[(y + 5) * 384 + x + 5];
}

extern "C" void kernel_launch(void* const* d_in, const int* in_sizes, int n_in,
                              void* d_out, int out_size, void* d_ws, size_t ws_size,
                              hipStream_t stream) {
    const float* mosaic = (const float*)d_in[0];
    const float* W0 = (const float*)d_in[1];  const float* b0 = (const float*)d_in[2];
    const float* W1 = (const float*)d_in[3];  const float* b1 = (const float*)d_in[4];
    const float* W2 = (const float*)d_in[5];  const float* b2 = (const float*)d_in[6];
    const float* W3 = (const float*)d_in[7];  const float* b3 = (const float*)d_in[8];
    const float* W4 = (const float*)d_in[9];  const float* b4 = (const float*)d_in[10];
    float* out = (float*)d_out;

    // workspace layout (bytes, all 16B aligned):
    //   x0f   f32  2*4*384*384          =  4,718,592 B
    //   Wq1-3 bf16 9*64*64 each         =     73,728 B each
    //   Wq4   bf16 9*512*64             =    589,824 B
    //   bufA  bf16 2*382*382*64         = 37,356,544 B
    //   bufB  bf16 2*380*380*64         = 36,966,400 B
    //   kst   f32  2*34*374*512         = 52,084,736 B   (total ~132 MB)
    char* ws = (char*)d_ws;
    float* x0f = (float*)ws;                       ws += 4718592;
    short* Wq1 = (short*)ws;                       ws += 73728;
    short* Wq2 = (short*)ws;                       ws += 73728;
    short* Wq3 = (short*)ws;                       ws += 73728;
    short* Wq4 = (short*)ws;                       ws += 589824;
    short* bufA = (short*)ws;                      ws += 37356544;
    short* bufB = (short*)ws;                      ws += 36966400;
    float* kst = (float*)ws;

    split_k<<<(2 * 4 * 384 * 384 + 255) / 256, 256, 0, stream>>>(mosaic, x0f);

    repack_k<<<(9 * 64 * 64 + 255) / 256, 256, 0, stream>>>(W1, 64, 64, Wq1);
    repack_k<<<(9 * 64 * 64 + 255) / 256, 256, 0, stream>>>(W2, 64, 64, Wq2);
    repack_k<<<(9 * 64 * 64 + 255) / 256, 256, 0, stream>>>(W3, 64, 64, Wq3);
    repack_k<<<(9 * 512 * 64 + 255) / 256, 256, 0, stream>>>(W4, 490, 512, Wq4);

    conv0_k<<<(2 * 382 * 382 + 255) / 256, 256, 0, stream>>>(x0f, W0, b0, bufA);

    // conv1: 382 -> 380
    convmfma_k<true, true><<<dim3(6, 380, 2), 256, 0, stream>>>(
        bufA, 382, 382, Wq1, b1, bufB, 64, 64, 64, 0, 380);
    // conv2: 380 -> 378
    convmfma_k<true, true><<<dim3(6, 378, 2), 256, 0, stream>>>(
        bufB, 380, 380, Wq2, b2, bufA, 64, 64, 64, 0, 378);
    // conv3: 378 -> 376
    convmfma_k<true, true><<<dim3(6, 376, 2), 256, 0, stream>>>(
        bufA, 378, 378, Wq3, b3, bufB, 64, 64, 64, 0, 376);

    // conv4 (64->490 pad 512, 376 -> 374) in 11 strips of 34 rows, each
    // consumed by the fused softmax/gather/pixel-shuffle epilogue.
    for (int ys = 0; ys < 374; ys += 34) {
        const int yc = 34;
        convmfma_k<false, false><<<dim3(6, yc, 2 * 8), 256, 0, stream>>>(
            bufB, 376, 376, Wq4, b4, kst, 490, 512, 512, ys, yc);
        epilogue_k<<<dim3(12, yc, 2), 256, 0, stream>>>(kst, x0f, out, ys, yc);
    }
}

// Round 3
// 511.258 us; speedup vs baseline: 30.1428x; 3.6881x over previous
//
#include <hip/hip_runtime.h>
#include <hip/hip_bf16.h>
#include <math.h>

// ---------------------------------------------------------------------------
// BayerKP demosaic KPN. R3: conv4 + softmax epilogue fully fused.
//   split    : gray sum + phase split -> x0f f32 (2,4,384,384) NCHW
//   conv0    : direct f32 4->64 ReLU -> NHWC bf16
//   conv1-3  : MFMA bf16 implicit GEMM, ReLU, NHWC bf16
//   conv4epi : MFMA with PERMUTED oc (10 softmax groups zero-padded to 64 oc
//              each, 640 total, 5 z-blocks of BM=128), softmax + 7x7 gather
//              + pixel-shuffle write, all in-register. No logit HBM traffic.
//   raw_k    : the 4 passthrough phase pixels.
// ---------------------------------------------------------------------------

typedef __attribute__((ext_vector_type(8))) short short8;
typedef __attribute__((ext_vector_type(4))) short short4v;
typedef __attribute__((ext_vector_type(4))) float f32x4;

static __device__ __forceinline__ short f2bf(float v) {
    __bf16 h = (__bf16)v;
    return __builtin_bit_cast(short, h);
}

__global__ __launch_bounds__(256) void split_k(const float* __restrict__ mosaic,
                                               float* __restrict__ x0) {
    int idx = blockIdx.x * 256 + threadIdx.x;
    const int total = 2 * 4 * 384 * 384;
    if (idx >= total) return;
    int x = idx % 384;
    int t = idx / 384;
    int y = t % 384;  t /= 384;
    int c = t % 4;
    int b = t / 4;
    int Y = 2 * y + ((c == 1 || c == 3) ? 1 : 0);
    int X = 2 * x + ((c == 2 || c == 3) ? 1 : 0);
    const float* mb = mosaic + (size_t)b * 3 * 768 * 768;
    float g = mb[Y * 768 + X] + mb[768 * 768 + Y * 768 + X] + mb[2 * 768 * 768 + Y * 768 + X];
    x0[idx] = g;
}

// repack W[Cout][64][3][3] f32 -> Wq[9][Cout][64] bf16 (conv1-3)
__global__ __launch_bounds__(256) void repack_k(const float* __restrict__ W,
                                                short* __restrict__ dst) {
    int idx = blockIdx.x * 256 + threadIdx.x;
    if (idx >= 9 * 64 * 64) return;
    int ic = idx % 64;
    int t2 = idx / 64;
    int oc = t2 % 64;
    int t  = t2 / 64;
    dst[idx] = f2bf(W[((size_t)oc * 64 + ic) * 9 + t]);
}

// conv4 repack with channel PERMUTATION: oc_new in [0,640), group k = oc_new/64,
// slot ql = oc_new%64; orig channel = 49*k + ql for ql<49, else zero-pad.
__global__ __launch_bounds__(256) void repack4_k(const float* __restrict__ W4,
                                                 const float* __restrict__ b4,
                                                 short* __restrict__ Wq,
                                                 float* __restrict__ bq) {
    int idx = blockIdx.x * 256 + threadIdx.x;
    if (idx < 9 * 640 * 64) {
        int ic  = idx % 64;
        int t2  = idx / 64;
        int ocn = t2 % 640;
        int tap = t2 / 640;
        int k  = ocn >> 6;
        int ql = ocn & 63;
        float v = (ql < 49) ? W4[((size_t)(49 * k + ql) * 64 + ic) * 9 + tap] : 0.f;
        Wq[idx] = f2bf(v);
    }
    if (idx < 640) {
        int k = idx >> 6, ql = idx & 63;
        bq[idx] = (ql < 49) ? b4[49 * k + ql] : 0.f;
    }
}

// conv0: direct f32, Cin=4, 384->382, ReLU, output NHWC bf16
__global__ __launch_bounds__(256) void conv0_k(const float* __restrict__ x0f,
                                               const float* __restrict__ W0,
                                               const float* __restrict__ b0,
                                               short* __restrict__ out) {
    __shared__ float w[64 * 36];
    __shared__ float bb[64];
    for (int e = threadIdx.x; e < 64 * 36; e += 256) w[e] = W0[e];
    if (threadIdx.x < 64) bb[threadIdx.x] = b0[threadIdx.x];
    __syncthreads();
    int idx = blockIdx.x * 256 + threadIdx.x;
    if (idx >= 2 * 382 * 382) return;
    int x = idx % 382;
    int t = idx / 382;
    int y = t % 382;
    int b = t / 382;
    const float* base = x0f + (size_t)b * 4 * 384 * 384;
    float in[4][9];
#pragma unroll
    for (int ic = 0; ic < 4; ++ic)
#pragma unroll
        for (int ky = 0; ky < 3; ++ky)
#pragma unroll
            for (int kx = 0; kx < 3; ++kx)
                in[ic][ky * 3 + kx] = base[ic * 384 * 384 + (y + ky) * 384 + (x + kx)];
    short* op = out + (((size_t)b * 382 + y) * 382 + x) * 64;
    float accs[8];
    for (int og = 0; og < 8; ++og) {
#pragma unroll
        for (int oo = 0; oo < 8; ++oo) {
            int oc = og * 8 + oo;
            float acc = bb[oc];
            const float* wp = w + oc * 36;
#pragma unroll
            for (int ic = 0; ic < 4; ++ic)
#pragma unroll
                for (int e = 0; e < 9; ++e)
                    acc = fmaf(in[ic][e], wp[ic * 9 + e], acc);
            accs[oo] = fmaxf(acc, 0.f);
        }
        short8 pk;
#pragma unroll
        for (int oo = 0; oo < 8; ++oo) pk[oo] = f2bf(accs[oo]);
        *(short8*)(op + og * 8) = pk;
    }
}

// Implicit-GEMM 3x3 conv via mfma_f32_16x16x32_bf16 (conv1-3).
// Block 256 = 4 waves (2x2). Tile: 64 oc x 64 px. K: 9 taps x 64 ic.
__global__ __launch_bounds__(256) void convmfma_k(
    const short* __restrict__ act, int Hin, int Win,
    const short* __restrict__ Wq, const float* __restrict__ bias,
    short* __restrict__ out) {
    const int Wout = Win - 2;
    const int b   = blockIdx.z;
    const int y   = blockIdx.y;
    const int x0  = blockIdx.x * 64;
    const int tid  = threadIdx.x;
    const int wave = tid >> 6;
    const int lane = tid & 63;
    const int wr = wave >> 1, wc = wave & 1;

    __shared__ __align__(16) short At[64][72];
    __shared__ __align__(16) short Bt[64][72];

    const int srow = tid >> 2;
    const int sq   = tid & 3;

    short8 ra0, ra1, rb0, rb1;
    auto loadA = [&](int tap) {
        const short* p = Wq + ((size_t)tap * 64 + srow) * 64 + sq * 16;
        ra0 = *(const short8*)p;
        ra1 = *(const short8*)(p + 8);
    };
    auto loadB = [&](int tap) {
        int ky = tap / 3, kx = tap % 3;
        int xe = x0 + srow;
        if (xe > Wout - 1) xe = Wout - 1;
        xe += kx;
        const short* p = act + (((size_t)b * Hin + (y + ky)) * (size_t)Win + xe) * 64 + sq * 16;
        rb0 = *(const short8*)p;
        rb1 = *(const short8*)(p + 8);
    };

    f32x4 acc[2][2] = {};
    loadA(0);
    loadB(0);
#pragma unroll 1
    for (int tap = 0; tap < 9; ++tap) {
        if (tap) __syncthreads();
        *(short8*)&At[srow][sq * 16]     = ra0;
        *(short8*)&At[srow][sq * 16 + 8] = ra1;
        *(short8*)&Bt[srow][sq * 16]     = rb0;
        *(short8*)&Bt[srow][sq * 16 + 8] = rb1;
        __syncthreads();
        if (tap < 8) { loadA(tap + 1); loadB(tap + 1); }
        short8 af[2][2], bf[2][2];
#pragma unroll
        for (int kk = 0; kk < 2; ++kk) {
            int ic = kk * 32 + (lane >> 4) * 8;
#pragma unroll
            for (int m = 0; m < 2; ++m)
                af[kk][m] = *(const short8*)&At[wr * 32 + m * 16 + (lane & 15)][ic];
#pragma unroll
            for (int n = 0; n < 2; ++n)
                bf[kk][n] = *(const short8*)&Bt[wc * 32 + n * 16 + (lane & 15)][ic];
        }
#pragma unroll
        for (int kk = 0; kk < 2; ++kk)
#pragma unroll
            for (int m = 0; m < 2; ++m)
#pragma unroll
                for (int n = 0; n < 2; ++n)
                    acc[m][n] = __builtin_amdgcn_mfma_f32_16x16x32_bf16(
                        af[kk][m], bf[kk][n], acc[m][n], 0, 0, 0);
    }

#pragma unroll
    for (int m = 0; m < 2; ++m) {
        int ocb = wr * 32 + m * 16 + (lane >> 4) * 4;
#pragma unroll
        for (int n = 0; n < 2; ++n) {
            int x = x0 + wc * 32 + n * 16 + (lane & 15);
            if (x >= Wout) continue;
            size_t off = (((size_t)b * Wout + y) * Wout + x) * 64 + ocb;
            short4v pk;
#pragma unroll
            for (int r = 0; r < 4; ++r)
                pk[r] = f2bf(fmaxf(acc[m][n][r] + bias[ocb + r], 0.f));
            *(short4v*)(out + off) = pk;
        }
    }
}

// Fused conv4 + softmax + gather + pixel-shuffle.
// BM=128 oc (two 64-oc softmax groups), BN=64 px, 4 waves as 2(M-wr) x 2(N-wc).
// z in [0,5): z<3 -> two independent 49-groups; z>=3 -> one 98 green group
// split across wr (wr0 gathers from g0, wr1 from g1), combined via LDS.
__global__ __launch_bounds__(256) void conv4epi_k(
    const short* __restrict__ act,   // conv3 out NHWC bf16 [2][376][376][64]
    const short* __restrict__ Wq,    // [9][640][64] bf16 permuted
    const float* __restrict__ bias,  // [640] permuted
    const float* __restrict__ x0f,   // [2][4][384][384] f32
    float* __restrict__ out) {       // [2][3][748][748]
    const int Hin = 376, Win = 376, Wout = 374;
    const int z5 = blockIdx.z;
    const int b = z5 / 5;
    const int z = z5 % 5;
    const int y = blockIdx.y;
    const int x0c = blockIdx.x * 64;
    const int tid = threadIdx.x;
    const int wave = tid >> 6;
    const int lane = tid & 63;
    const int wr = wave >> 1, wc = wave & 1;
    const int l15 = lane & 15, l4 = lane >> 4;

    __shared__ __align__(16) short At[128][72];
    __shared__ __align__(16) short Bt[64][72];
    __shared__ float smM[2][64], smD[2][64], smN[2][64];

    const int arow = tid >> 1;  // 0..127
    const int ah   = tid & 1;   // 32-ic half
    const int brow = tid >> 2;  // 0..63
    const int bq   = tid & 3;   // 16-ic quarter

    short8 ra0, ra1, ra2, ra3, rb0, rb1;
    auto loadA = [&](int tap) {
        const short* p = Wq + ((size_t)tap * 640 + z * 128 + arow) * 64 + ah * 32;
        ra0 = *(const short8*)p;
        ra1 = *(const short8*)(p + 8);
        ra2 = *(const short8*)(p + 16);
        ra3 = *(const short8*)(p + 24);
    };
    auto loadB = [&](int tap) {
        int ky = tap / 3, kx = tap % 3;
        int xe = x0c + brow;
        if (xe > Wout - 1) xe = Wout - 1;
        xe += kx;
        const short* p = act + (((size_t)b * Hin + (y + ky)) * (size_t)Win + xe) * 64 + bq * 16;
        rb0 = *(const short8*)p;
        rb1 = *(const short8*)(p + 8);
    };

    f32x4 acc[4][2] = {};
    loadA(0);
    loadB(0);
#pragma unroll 1
    for (int tap = 0; tap < 9; ++tap) {
        if (tap) __syncthreads();
        *(short8*)&At[arow][ah * 32]      = ra0;
        *(short8*)&At[arow][ah * 32 + 8]  = ra1;
        *(short8*)&At[arow][ah * 32 + 16] = ra2;
        *(short8*)&At[arow][ah * 32 + 24] = ra3;
        *(short8*)&Bt[brow][bq * 16]      = rb0;
        *(short8*)&Bt[brow][bq * 16 + 8]  = rb1;
        __syncthreads();
        if (tap < 8) { loadA(tap + 1); loadB(tap + 1); }
        short8 af[2][4], bf[2][2];
#pragma unroll
        for (int kk = 0; kk < 2; ++kk) {
            int ic = kk * 32 + l4 * 8;
#pragma unroll
            for (int m = 0; m < 4; ++m)
                af[kk][m] = *(const short8*)&At[wr * 64 + m * 16 + l15][ic];
#pragma unroll
            for (int n = 0; n < 2; ++n)
                bf[kk][n] = *(const short8*)&Bt[wc * 32 + n * 16 + l15][ic];
        }
#pragma unroll
        for (int kk = 0; kk < 2; ++kk)
#pragma unroll
            for (int m = 0; m < 4; ++m)
#pragma unroll
                for (int n = 0; n < 2; ++n)
                    acc[m][n] = __builtin_amdgcn_mfma_f32_16x16x32_bf16(
                        af[kk][m], bf[kk][n], acc[m][n], 0, 0, 0);
    }

    // ---- fused epilogue ----
    // gather plane per (z, wr): z0:(rr,rr) z1:(rr,bl) z2:(bl,bl) z3/4:(g0,g1)
    const float* pb = x0f + (size_t)b * 4 * 384 * 384;
    int pidx;
    switch (z) {
        case 0: pidx = 2; break;
        case 1: pidx = wr ? 1 : 2; break;
        case 2: pidx = 1; break;
        default: pidx = wr ? 3 : 0; break;
    }
    const float* plane = pb + (size_t)pidx * 384 * 384;

    float bv[4][4];
#pragma unroll
    for (int m = 0; m < 4; ++m)
#pragma unroll
        for (int r = 0; r < 4; ++r)
            bv[m][r] = bias[z * 128 + wr * 64 + m * 16 + l4 * 4 + r];

#pragma unroll
    for (int n = 0; n < 2; ++n) {
        const int xn = x0c + wc * 32 + n * 16 + l15;
        const int xg = (xn < Wout) ? xn : (Wout - 1);  // clamp (write is guarded)
        float mx = -1e30f;
#pragma unroll
        for (int m = 0; m < 4; ++m)
#pragma unroll
            for (int r = 0; r < 4; ++r) {
                int q = m * 16 + l4 * 4 + r;
                if (q < 49) mx = fmaxf(mx, acc[m][n][r] + bv[m][r]);
            }
        mx = fmaxf(mx, __shfl_xor(mx, 16));
        mx = fmaxf(mx, __shfl_xor(mx, 32));
        float den = 0.f, num = 0.f;
#pragma unroll
        for (int m = 0; m < 4; ++m)
#pragma unroll
            for (int r = 0; r < 4; ++r) {
                int q = m * 16 + l4 * 4 + r;
                if (q < 49) {
                    float e = __expf(acc[m][n][r] + bv[m][r] - mx);
                    den += e;
                    float g = plane[(y + 2 + q / 7) * 384 + (xg + 2 + q % 7)];
                    num = fmaf(e, g, num);
                }
            }
        den += __shfl_xor(den, 16);  den += __shfl_xor(den, 32);
        num += __shfl_xor(num, 16);  num += __shfl_xor(num, 32);
        if (l4 == 0) {
            int p = wc * 32 + n * 16 + l15;
            smM[wr][p] = mx;
            smD[wr][p] = den;
            smN[wr][p] = num;
        }
    }
    __syncthreads();

    if (z < 3) {
        // two independent groups; task id = z*2+sub (matches R2 tasks 0..5)
        if (tid < 128) {
            int sub = tid >> 6, p = tid & 63;
            int x = x0c + p;
            if (x < Wout) {
                float val = smN[sub][p] / smD[sub][p];
                int t = z * 2 + sub;
                int color = (t < 3) ? 0 : 2;
                int oy, ox;
                switch (t) {
                    case 0: oy = 0; ox = 0; break;
                    case 1: oy = 1; ox = 0; break;
                    case 2: oy = 1; ox = 1; break;
                    case 3: oy = 0; ox = 0; break;
                    case 4: oy = 0; ox = 1; break;
                    default: oy = 1; ox = 1; break;
                }
                out[(((size_t)b * 3 + color) * 748 + 2 * y + oy) * 748 + 2 * x + ox] = val;
            }
        }
    } else {
        // green: combine the two 49-halves with max-rescale
        if (tid < 64) {
            int p = tid, x = x0c + p;
            if (x < Wout) {
                float m0 = smM[0][p], m1 = smM[1][p];
                float M = fmaxf(m0, m1);
                float s0 = __expf(m0 - M), s1 = __expf(m1 - M);
                float val = (smN[0][p] * s0 + smN[1][p] * s1) /
                            (smD[0][p] * s0 + smD[1][p] * s1);
                int oy = (z == 3) ? 0 : 1;
                int ox = (z == 3) ? 1 : 0;
                out[(((size_t)b * 3 + 1) * 748 + 2 * y + oy) * 748 + 2 * x + ox] = val;
            }
        }
    }
}

// raw passthrough pixels: red (0,1), blue (1,0), green g0 (0,0), green g1 (1,1)
__global__ __launch_bounds__(256) void raw_k(const float* __restrict__ x0f,
                                             float* __restrict__ out) {
    int idx = blockIdx.x * 256 + threadIdx.x;
    if (idx >= 2 * 374 * 374) return;
    int x = idx % 374;
    int t = idx / 374;
    int y = t % 374;
    int b = t / 374;
    const float* pb = x0f + (size_t)b * 4 * 384 * 384;
    float g0v = pb[(y + 5) * 384 + x + 5];
    float blv = pb[384 * 384 + (y + 5) * 384 + x + 5];
    float rrv = pb[2 * 384 * 384 + (y + 5) * 384 + x + 5];
    float g1v = pb[3 * 384 * 384 + (y + 5) * 384 + x + 5];
    float* ob = out + (size_t)b * 3 * 748 * 748;
    ob[((size_t)0 * 748 + 2 * y) * 748 + 2 * x + 1]     = rrv;
    ob[((size_t)2 * 748 + 2 * y + 1) * 748 + 2 * x]     = blv;
    ob[((size_t)1 * 748 + 2 * y) * 748 + 2 * x]         = g0v;
    ob[((size_t)1 * 748 + 2 * y + 1) * 748 + 2 * x + 1] = g1v;
}

extern "C" void kernel_launch(void* const* d_in, const int* in_sizes, int n_in,
                              void* d_out, int out_size, void* d_ws, size_t ws_size,
                              hipStream_t stream) {
    const float* mosaic = (const float*)d_in[0];
    const float* W0 = (const float*)d_in[1];  const float* b0 = (const float*)d_in[2];
    const float* W1 = (const float*)d_in[3];  const float* b1 = (const float*)d_in[4];
    const float* W2 = (const float*)d_in[5];  const float* b2 = (const float*)d_in[6];
    const float* W3 = (const float*)d_in[7];  const float* b3 = (const float*)d_in[8];
    const float* W4 = (const float*)d_in[9];  const float* b4 = (const float*)d_in[10];
    float* out = (float*)d_out;

    // workspace (bytes):
    //   x0f    f32  2*4*384*384       =  4,718,592
    //   Wq1-3  bf16 9*64*64           =     73,728 each
    //   Wq4p   bf16 9*640*64          =    737,280
    //   bias4p f32  640               =      2,560
    //   bufA   bf16 2*382*382*64      = 37,356,544
    //   bufB   bf16 2*380*380*64      = 36,966,400    total ~80 MB
    char* ws = (char*)d_ws;
    float* x0f    = (float*)ws;  ws += 4718592;
    short* Wq1    = (short*)ws;  ws += 73728;
    short* Wq2    = (short*)ws;  ws += 73728;
    short* Wq3    = (short*)ws;  ws += 73728;
    short* Wq4p   = (short*)ws;  ws += 737280;
    float* bias4p = (float*)ws;  ws += 2560;
    short* bufA   = (short*)ws;  ws += 37356544;
    short* bufB   = (short*)ws;

    split_k<<<(2 * 4 * 384 * 384 + 255) / 256, 256, 0, stream>>>(mosaic, x0f);

    repack_k<<<(9 * 64 * 64 + 255) / 256, 256, 0, stream>>>(W1, Wq1);
    repack_k<<<(9 * 64 * 64 + 255) / 256, 256, 0, stream>>>(W2, Wq2);
    repack_k<<<(9 * 64 * 64 + 255) / 256, 256, 0, stream>>>(W3, Wq3);
    repack4_k<<<(9 * 640 * 64 + 255) / 256, 256, 0, stream>>>(W4, b4, Wq4p, bias4p);

    conv0_k<<<(2 * 382 * 382 + 255) / 256, 256, 0, stream>>>(x0f, W0, b0, bufA);

    convmfma_k<<<dim3(6, 380, 2), 256, 0, stream>>>(bufA, 382, 382, Wq1, b1, bufB);
    convmfma_k<<<dim3(6, 378, 2), 256, 0, stream>>>(bufB, 380, 380, Wq2, b2, bufA);
    convmfma_k<<<dim3(6, 376, 2), 256, 0, stream>>>(bufA, 378, 378, Wq3, b3, bufB);

    conv4epi_k<<<dim3(6, 374, 2 * 5), 256, 0, stream>>>(bufB, Wq4p, bias4p, x0f, out);
    raw_k<<<(2 * 374 * 374 + 255) / 256, 256, 0, stream>>>(x0f, out);
}